// Round 5
// baseline (299.723 us; speedup 1.0000x reference)
//
#include <hip/hip_runtime.h>
#include <stdint.h>

#define IN_F   4096
#define OUT_F  4096
#define M_TOT  8192
#define KDIM   4096

typedef float          f32x4  __attribute__((ext_vector_type(4)));
typedef int            i32x4  __attribute__((ext_vector_type(4)));
typedef unsigned short u16x8  __attribute__((ext_vector_type(8)));
typedef __bf16         bf16x8 __attribute__((ext_vector_type(8)));

// round-to-nearest-even f32 -> bf16
__device__ __forceinline__ unsigned short f2bf(float f) {
  uint32_t u = __builtin_bit_cast(uint32_t, f);
  u = (u + 0x7FFFu + ((u >> 16) & 1u)) >> 16;
  return (unsigned short)u;
}
__device__ __forceinline__ float bf2f(unsigned short s) {
  return __builtin_bit_cast(float, (uint32_t)s << 16);
}

// async global->LDS, 16B/lane; LDS dest = wave-uniform base + lane*16 (linear)
__device__ __forceinline__ void gld_lds16(const void* g, void* l) {
  __builtin_amdgcn_global_load_lds((const __attribute__((address_space(1))) void*)g,
                                   (__attribute__((address_space(3))) void*)l,
                                   16, 0, 0);
}

// ---------- kernel 1: x (fp32) -> bf16, 8 elems/thread ----------
__global__ __launch_bounds__(256) void k_xcast(const f32x4* __restrict__ x,
                                               u16x8* __restrict__ xb) {
  int t = blockIdx.x * 256 + threadIdx.x;
  f32x4 a = x[2 * t];
  f32x4 b = x[2 * t + 1];
  u16x8 o;
  o[0] = f2bf(a[0]); o[1] = f2bf(a[1]); o[2] = f2bf(a[2]); o[3] = f2bf(a[3]);
  o[4] = f2bf(b[0]); o[5] = f2bf(b[1]); o[6] = f2bf(b[2]); o[7] = f2bf(b[3]);
  xb[t] = o;
}

// ---------- kernel 2: L[o][i] = bf16( 2.0 * sum_r A[i][r]*B[r][o] )  (into d_out scratch) ----------
__global__ __launch_bounds__(256) void k_lora(const float* __restrict__ A,   // [IN_F][16]
                                              const float* __restrict__ Bm,  // [16][OUT_F]
                                              unsigned short* __restrict__ L) { // [OUT_F][IN_F] bf16
  __shared__ float sB[16][64];
  const int ib = blockIdx.x * 256;
  const int ob = blockIdx.y * 64;
  const int t  = threadIdx.x;
  for (int j = 0; j < 4; ++j) {
    int idx = t + j * 256;
    int r = idx >> 6, oc = idx & 63;
    sB[r][oc] = Bm[r * OUT_F + ob + oc];
  }
  float a[16];
  const f32x4* Ap = (const f32x4*)(A + (size_t)(ib + t) * 16);
  #pragma unroll
  for (int j = 0; j < 4; ++j) {
    f32x4 v = Ap[j];
    a[4*j+0] = v[0]; a[4*j+1] = v[1]; a[4*j+2] = v[2]; a[4*j+3] = v[3];
  }
  __syncthreads();
  unsigned short* Lp = L + (size_t)ob * IN_F + ib + t;
  #pragma unroll 4
  for (int oc = 0; oc < 64; ++oc) {
    float acc = 0.f;
    #pragma unroll
    for (int r = 0; r < 16; ++r) acc += a[r] * sB[r][oc];
    Lp[(size_t)oc * IN_F] = f2bf(acc * 2.0f);   // LORA_SCALE = 32/16
  }
}

// ---------- kernel 3: dequant INT4 + merge L -> Wc bf16 [OUT_F][IN_F] ----------
__global__ __launch_bounds__(256) void k_dequant(const int* __restrict__ idx,
                                                 const float* __restrict__ cb,
                                                 const float* __restrict__ scales,
                                                 const unsigned short* __restrict__ L,
                                                 unsigned short* __restrict__ Wc) {
  __shared__ float scb[16];
  const int t = blockIdx.x * 256 + threadIdx.x;
  if (threadIdx.x < 16) scb[threadIdx.x] = cb[threadIdx.x];
  __syncthreads();
  i32x4 w = ((const i32x4*)idx)[t];
  float sc = scales[t >> 4];
  u16x8 lw = ((const u16x8*)L)[t];
  u16x8 o;
  #pragma unroll
  for (int j = 0; j < 4; ++j) {
    int word = w[j];
    float v0 = scb[word & 15] * sc + bf2f(lw[2 * j]);
    float v1 = scb[(word >> 4) & 15] * sc + bf2f(lw[2 * j + 1]);
    o[2 * j]     = f2bf(v0);
    o[2 * j + 1] = f2bf(v1);
  }
  ((u16x8*)Wc)[t] = o;
}

// ---------- kernel 4: 256x256 8-phase bf16 GEMM (m201-style template) ----------
// C[m][n] = sum_k A[m][k]*B[n][k] + bias[n];  A:[8192][4096] bf16, B:[4096][4096] bf16.
// 512 threads = 8 waves (2M x 4N); per-wave output 128x64; BK=64; 128 KiB static LDS dbuf.
// LDS layout (bytes): A buf c at c*32768 (256 rows x 128B); B buf c at 65536+c*32768.
// Swizzle: logical 16B-slot s of row is stored at physical slot s^(row&7);
// applied via pre-swizzled global source (linear gld_lds dest) + XOR on ds_read.
// XCD-aware chunked blockIdx swizzle: 512 blocks, 64 consecutive tiles per XCD.

#define BARR()  __builtin_amdgcn_s_barrier()
#define LGKM0() asm volatile("s_waitcnt lgkmcnt(0)" ::: "memory")
#define VMC6()  asm volatile("s_waitcnt vmcnt(6)" ::: "memory")
#define VMC0()  asm volatile("s_waitcnt vmcnt(0)" ::: "memory")

#define STAGE_A(kt, ha, c) do {                                                          \
  gld_lds16(Ag + (size_t)((ha) * 128) * KDIM + (kt) * 64,                                \
            smem + (c) * 32768 + (ha) * 16384 + ldsw);                                   \
  gld_lds16(Ag + (size_t)((ha) * 128 + 64) * KDIM + (kt) * 64,                           \
            smem + (c) * 32768 + (ha) * 16384 + 8192 + ldsw);                            \
} while (0)

#define STAGE_B(kt, hb, c) do {                                                          \
  gld_lds16(Bg + (size_t)((hb) * 128) * KDIM + (kt) * 64,                                \
            smem + 65536 + (c) * 32768 + (hb) * 16384 + ldsw);                           \
  gld_lds16(Bg + (size_t)((hb) * 128 + 64) * KDIM + (kt) * 64,                           \
            smem + 65536 + (c) * 32768 + (hb) * 16384 + 8192 + ldsw);                    \
} while (0)

#define LOAD_A(qm, c) do {                                                               \
  const char* _p = smem + (c) * 32768 + rowA + (qm) * 8192;                              \
  _Pragma("unroll")                                                                      \
  for (int mi = 0; mi < 4; ++mi) {                                                       \
    af[mi][0] = *(const bf16x8*)(_p + mi * 2048 + coff0);                                \
    af[mi][1] = *(const bf16x8*)(_p + mi * 2048 + coff1);                                \
  }                                                                                      \
} while (0)

#define LOAD_B01(c) do {                                                                 \
  const char* _p = smem + 65536 + (c) * 32768 + rowB;                                    \
  _Pragma("unroll")                                                                      \
  for (int ni = 0; ni < 2; ++ni) {                                                       \
    bfr[ni][0] = *(const bf16x8*)(_p + ni * 2048 + coff0);                               \
    bfr[ni][1] = *(const bf16x8*)(_p + ni * 2048 + coff1);                               \
  }                                                                                      \
} while (0)

#define LOAD_B23(c) do {                                                                 \
  const char* _p = smem + 65536 + (c) * 32768 + rowB;                                    \
  _Pragma("unroll")                                                                      \
  for (int ni = 2; ni < 4; ++ni) {                                                       \
    bfr[ni][0] = *(const bf16x8*)(_p + ni * 2048 + coff0);                               \
    bfr[ni][1] = *(const bf16x8*)(_p + ni * 2048 + coff1);                               \
  }                                                                                      \
} while (0)

#define MFMA_PH(qm, nb) do {                                                             \
  __builtin_amdgcn_s_setprio(1);                                                         \
  _Pragma("unroll")                                                                      \
  for (int mi = 0; mi < 4; ++mi)                                                         \
    _Pragma("unroll")                                                                    \
    for (int nj = 0; nj < 2; ++nj)                                                       \
      _Pragma("unroll")                                                                  \
      for (int kk = 0; kk < 2; ++kk)                                                     \
        acc[(qm) * 4 + mi][(nb) * 2 + nj] = __builtin_amdgcn_mfma_f32_16x16x32_bf16(     \
            af[mi][kk], bfr[(nb) * 2 + nj][kk], acc[(qm) * 4 + mi][(nb) * 2 + nj],       \
            0, 0, 0);                                                                    \
  __builtin_amdgcn_s_setprio(0);                                                         \
} while (0)

// One K-tile = 4 phases; ds-reads balanced 12/4/8/0.
// B-buf c reads retire at ph1's lgkm0+barrier -> B-buf c restaged at ph2/ph3.
// A-buf c reads retire at ph2 -> A-buf c restaged at ph3.
// A-buf c^1 half1 (dead since prev tile) staged at ph0.
// vmcnt ledger: tile tau's 8 loads issue at (tau-2):ph2 [B0], (tau-2):ph3 [B1,A0],
// (tau-1):ph0 [A1]; at tile t ph3 drain, outstanding after t+1's loads = t's
// ph2+ph3 stages = 6  -> VMC6.
#define TILE(t_, c_, doS4, doS123, VMCODE) do {                                          \
  /* ph0 */                                                                              \
  LOAD_A(0, c_); LOAD_B01(c_);                                                           \
  if (doS4) STAGE_A((t_) + 1, 1, (c_) ^ 1);                                              \
  BARR(); LGKM0(); MFMA_PH(0, 0); BARR();                                                \
  /* ph1 */                                                                              \
  LOAD_B23(c_);                                                                          \
  BARR(); LGKM0(); MFMA_PH(0, 1); BARR();                                                \
  /* ph2 */                                                                              \
  LOAD_A(1, c_);                                                                         \
  if (doS123) STAGE_B((t_) + 2, 0, c_);                                                  \
  BARR(); LGKM0(); MFMA_PH(1, 1); BARR();                                                \
  /* ph3 */                                                                              \
  if (doS123) { STAGE_B((t_) + 2, 1, c_); STAGE_A((t_) + 2, 0, c_); }                    \
  BARR(); MFMA_PH(1, 0); VMCODE; BARR();                                                 \
} while (0)

__global__ __launch_bounds__(512, 2) void k_gemm(const unsigned short* __restrict__ A,
                                                 const unsigned short* __restrict__ B,
                                                 const float* __restrict__ bias,
                                                 float* __restrict__ C) {
  __shared__ char smem[131072];   // static 128 KiB (gfx950: 160 KiB/WG max)
  const int tid  = threadIdx.x;
  const int lane = tid & 63;
  const int wv   = tid >> 6;     // 0..7
  const int wm   = wv >> 2;      // 0..1
  const int wn   = wv & 3;       // 0..3
  const int r    = lane & 15;
  const int q    = lane >> 4;
  const int xr   = r & 7;
  const int coff0 = (q ^ xr) << 4;          // byte col for kk=0 (swizzled)
  const int coff1 = ((q + 4) ^ xr) << 4;    // byte col for kk=1
  const int rowA = (wm * 128 + r) * 128;    // byte row base in A tile
  const int rowB = (wn * 64 + r) * 128;     // byte row base in B tile
  const int srow = tid >> 3;                // 0..63 staging row
  const int scol = ((tid & 7) ^ ((tid >> 3) & 7)) * 8;  // pre-swizzled global elem col
  const int ldsw = wv * 1024;               // wave's byte slot in a staging round

  // XCD chunked swizzle (bijective: 512 % 8 == 0): XCD k gets sid [k*64,(k+1)*64)
  const int id  = blockIdx.x;               // 0..511
  const int sid = ((id & 7) << 6) | (id >> 3);
  const int bm  = sid & 31;                 // 0..31
  const int bn  = sid >> 5;                 // 0..15

  const unsigned short* Ag = A + (size_t)(bm * 256 + srow) * KDIM + scol;
  const unsigned short* Bg = B + (size_t)(bn * 256 + srow) * KDIM + scol;

  bf16x8 af[4][2], bfr[4][2];
  f32x4 acc[8][4];
  #pragma unroll
  for (int m = 0; m < 8; ++m)
    #pragma unroll
    for (int n = 0; n < 4; ++n)
      acc[m][n] = (f32x4){0.f, 0.f, 0.f, 0.f};

  // prologue: tile0 complete + 3 halves of tile1 (7 half-tiles, 14 loads/thread)
  STAGE_B(0, 0, 0); STAGE_B(0, 1, 0); STAGE_A(0, 0, 0); STAGE_A(0, 1, 0);
  STAGE_B(1, 0, 1); STAGE_B(1, 1, 1); STAGE_A(1, 0, 1);
  VMC6();   // tile0's 8 loads done; 6 in flight
  BARR();

  #pragma unroll 1
  for (int t = 0; t < 62; t += 2) {
    TILE(t,     0, 1, 1, VMC6());
    TILE(t + 1, 1, 1, 1, VMC6());
  }
  TILE(62, 0, 1, 0, VMC0());
  TILE(63, 1, 0, 0, VMC0());

  // epilogue: C = acc + bias  (C/D layout: col = r, row = q*4 + j)
  const int row0 = bm * 256 + wm * 128;
  const int col0 = bn * 256 + wn * 64;
  float bv[4];
  #pragma unroll
  for (int ni = 0; ni < 4; ++ni) bv[ni] = bias[col0 + ni * 16 + r];
  #pragma unroll
  for (int mi = 0; mi < 8; ++mi) {
    #pragma unroll
    for (int j = 0; j < 4; ++j) {
      const int row = row0 + mi * 16 + q * 4 + j;
      float* Cp = C + (size_t)row * OUT_F + col0 + r;
      #pragma unroll
      for (int ni = 0; ni < 4; ++ni)
        Cp[ni * 16] = acc[mi][ni][j] + bv[ni];
    }
  }
}

extern "C" void kernel_launch(void* const* d_in, const int* in_sizes, int n_in,
                              void* d_out, int out_size, void* d_ws, size_t ws_size,
                              hipStream_t stream) {
  const float* x    = (const float*)d_in[0];
  const int*   idx  = (const int*)d_in[1];
  const float* cb   = (const float*)d_in[2];
  const float* scl  = (const float*)d_in[3];
  const float* lA   = (const float*)d_in[4];
  const float* lB   = (const float*)d_in[5];
  const float* bias = (const float*)d_in[6];
  float* out = (float*)d_out;

  unsigned short* xb = (unsigned short*)d_ws;
  unsigned short* Wc = (unsigned short*)((char*)d_ws + (size_t)M_TOT * KDIM * 2);
  unsigned short* Lbuf = (unsigned short*)d_out;  // bf16 LoRA scratch (32MB of 128MB); overwritten by k_gemm

  k_xcast<<<16384, 256, 0, stream>>>((const f32x4*)x, (u16x8*)xb);
  k_lora<<<dim3(16, 64), 256, 0, stream>>>(lA, lB, Lbuf);
  k_dequant<<<8192, 256, 0, stream>>>(idx, cb, scl, Lbuf, Wc);
  k_gemm<<<512, 512, 0, stream>>>(xb, Wc, bias, out);
}

// Round 6
// 288.637 us; speedup vs baseline: 1.0384x; 1.0384x over previous
//
#include <hip/hip_runtime.h>
#include <stdint.h>

#define IN_F   4096
#define OUT_F  4096
#define M_TOT  8192
#define KDIM   4096

typedef float          f32x4  __attribute__((ext_vector_type(4)));
typedef int            i32x4  __attribute__((ext_vector_type(4)));
typedef unsigned short u16x8  __attribute__((ext_vector_type(8)));
typedef __bf16         bf16x8 __attribute__((ext_vector_type(8)));

// round-to-nearest-even f32 -> bf16
__device__ __forceinline__ unsigned short f2bf(float f) {
  uint32_t u = __builtin_bit_cast(uint32_t, f);
  u = (u + 0x7FFFu + ((u >> 16) & 1u)) >> 16;
  return (unsigned short)u;
}
__device__ __forceinline__ float bf2f(unsigned short s) {
  return __builtin_bit_cast(float, (uint32_t)s << 16);
}

// async global->LDS, 16B/lane; LDS dest = wave-uniform base + lane*16 (linear)
__device__ __forceinline__ void gld_lds16(const void* g, void* l) {
  __builtin_amdgcn_global_load_lds((const __attribute__((address_space(1))) void*)g,
                                   (__attribute__((address_space(3))) void*)l,
                                   16, 0, 0);
}

// ---------- kernel 1: x (fp32) -> bf16, 8 elems/thread ----------
__global__ __launch_bounds__(256) void k_xcast(const f32x4* __restrict__ x,
                                               u16x8* __restrict__ xb) {
  int t = blockIdx.x * 256 + threadIdx.x;
  f32x4 a = x[2 * t];
  f32x4 b = x[2 * t + 1];
  u16x8 o;
  o[0] = f2bf(a[0]); o[1] = f2bf(a[1]); o[2] = f2bf(a[2]); o[3] = f2bf(a[3]);
  o[4] = f2bf(b[0]); o[5] = f2bf(b[1]); o[6] = f2bf(b[2]); o[7] = f2bf(b[3]);
  xb[t] = o;
}

// ---------- kernel 2: L[o][i] = bf16( 2.0 * sum_r A[i][r]*B[r][o] )  (into d_out scratch) ----------
__global__ __launch_bounds__(256) void k_lora(const float* __restrict__ A,   // [IN_F][16]
                                              const float* __restrict__ Bm,  // [16][OUT_F]
                                              unsigned short* __restrict__ L) { // [OUT_F][IN_F] bf16
  __shared__ float sB[16][64];
  const int ib = blockIdx.x * 256;
  const int ob = blockIdx.y * 64;
  const int t  = threadIdx.x;
  for (int j = 0; j < 4; ++j) {
    int idx = t + j * 256;
    int r = idx >> 6, oc = idx & 63;
    sB[r][oc] = Bm[r * OUT_F + ob + oc];
  }
  float a[16];
  const f32x4* Ap = (const f32x4*)(A + (size_t)(ib + t) * 16);
  #pragma unroll
  for (int j = 0; j < 4; ++j) {
    f32x4 v = Ap[j];
    a[4*j+0] = v[0]; a[4*j+1] = v[1]; a[4*j+2] = v[2]; a[4*j+3] = v[3];
  }
  __syncthreads();
  unsigned short* Lp = L + (size_t)ob * IN_F + ib + t;
  #pragma unroll 4
  for (int oc = 0; oc < 64; ++oc) {
    float acc = 0.f;
    #pragma unroll
    for (int r = 0; r < 16; ++r) acc += a[r] * sB[r][oc];
    Lp[(size_t)oc * IN_F] = f2bf(acc * 2.0f);   // LORA_SCALE = 32/16
  }
}

// ---------- kernel 3: dequant INT4 + merge L -> Wc bf16 [OUT_F][IN_F] ----------
__global__ __launch_bounds__(256) void k_dequant(const int* __restrict__ idx,
                                                 const float* __restrict__ cb,
                                                 const float* __restrict__ scales,
                                                 const unsigned short* __restrict__ L,
                                                 unsigned short* __restrict__ Wc) {
  __shared__ float scb[16];
  const int t = blockIdx.x * 256 + threadIdx.x;
  if (threadIdx.x < 16) scb[threadIdx.x] = cb[threadIdx.x];
  __syncthreads();
  i32x4 w = ((const i32x4*)idx)[t];
  float sc = scales[t >> 4];
  u16x8 lw = ((const u16x8*)L)[t];
  u16x8 o;
  #pragma unroll
  for (int j = 0; j < 4; ++j) {
    int word = w[j];
    float v0 = scb[word & 15] * sc + bf2f(lw[2 * j]);
    float v1 = scb[(word >> 4) & 15] * sc + bf2f(lw[2 * j + 1]);
    o[2 * j]     = f2bf(v0);
    o[2 * j + 1] = f2bf(v1);
  }
  ((u16x8*)Wc)[t] = o;
}

// ---------- kernel 4: 256x256 8-phase bf16 GEMM (m201-style template) ----------
// C[m][n] = sum_k A[m][k]*B[n][k] + bias[n];  A:[8192][4096] bf16, B:[4096][4096] bf16.
// 512 threads = 8 waves (2M x 4N); per-wave output 128x64; BK=64; 128 KiB static LDS dbuf.
// LDS layout (bytes): A buf c at c*32768 (256 rows x 128B); B buf c at 65536+c*32768.
// Swizzle: logical 16B-slot s of row is stored at physical slot s^(row&7);
// applied via pre-swizzled global source (linear gld_lds dest) + XOR on ds_read.
// Grid: natural dim3(32,16) — resident set per XCD = 4bm x 8bn, ~384KB/K-step in L2.
// (Chunked XCD swizzle measured WORSE: FETCH 196->540MB, resident set all-bm x 1-bn.)

#define BARR()  __builtin_amdgcn_s_barrier()
#define LGKM0() asm volatile("s_waitcnt lgkmcnt(0)" ::: "memory")
#define VMC6()  asm volatile("s_waitcnt vmcnt(6)" ::: "memory")
#define VMC0()  asm volatile("s_waitcnt vmcnt(0)" ::: "memory")

#define STAGE_A(kt, ha, c) do {                                                          \
  gld_lds16(Ag + (size_t)((ha) * 128) * KDIM + (kt) * 64,                                \
            smem + (c) * 32768 + (ha) * 16384 + ldsw);                                   \
  gld_lds16(Ag + (size_t)((ha) * 128 + 64) * KDIM + (kt) * 64,                           \
            smem + (c) * 32768 + (ha) * 16384 + 8192 + ldsw);                            \
} while (0)

#define STAGE_B(kt, hb, c) do {                                                          \
  gld_lds16(Bg + (size_t)((hb) * 128) * KDIM + (kt) * 64,                                \
            smem + 65536 + (c) * 32768 + (hb) * 16384 + ldsw);                           \
  gld_lds16(Bg + (size_t)((hb) * 128 + 64) * KDIM + (kt) * 64,                           \
            smem + 65536 + (c) * 32768 + (hb) * 16384 + 8192 + ldsw);                    \
} while (0)

#define LOAD_A(qm, c) do {                                                               \
  const char* _p = smem + (c) * 32768 + rowA + (qm) * 8192;                              \
  _Pragma("unroll")                                                                      \
  for (int mi = 0; mi < 4; ++mi) {                                                       \
    af[mi][0] = *(const bf16x8*)(_p + mi * 2048 + coff0);                                \
    af[mi][1] = *(const bf16x8*)(_p + mi * 2048 + coff1);                                \
  }                                                                                      \
} while (0)

#define LOAD_B01(c) do {                                                                 \
  const char* _p = smem + 65536 + (c) * 32768 + rowB;                                    \
  _Pragma("unroll")                                                                      \
  for (int ni = 0; ni < 2; ++ni) {                                                       \
    bfr[ni][0] = *(const bf16x8*)(_p + ni * 2048 + coff0);                               \
    bfr[ni][1] = *(const bf16x8*)(_p + ni * 2048 + coff1);                               \
  }                                                                                      \
} while (0)

#define LOAD_B23(c) do {                                                                 \
  const char* _p = smem + 65536 + (c) * 32768 + rowB;                                    \
  _Pragma("unroll")                                                                      \
  for (int ni = 2; ni < 4; ++ni) {                                                       \
    bfr[ni][0] = *(const bf16x8*)(_p + ni * 2048 + coff0);                               \
    bfr[ni][1] = *(const bf16x8*)(_p + ni * 2048 + coff1);                               \
  }                                                                                      \
} while (0)

#define MFMA_PH(qm, nb) do {                                                             \
  __builtin_amdgcn_s_setprio(1);                                                         \
  _Pragma("unroll")                                                                      \
  for (int mi = 0; mi < 4; ++mi)                                                         \
    _Pragma("unroll")                                                                    \
    for (int nj = 0; nj < 2; ++nj)                                                       \
      _Pragma("unroll")                                                                  \
      for (int kk = 0; kk < 2; ++kk)                                                     \
        acc[(qm) * 4 + mi][(nb) * 2 + nj] = __builtin_amdgcn_mfma_f32_16x16x32_bf16(     \
            af[mi][kk], bfr[(nb) * 2 + nj][kk], acc[(qm) * 4 + mi][(nb) * 2 + nj],       \
            0, 0, 0);                                                                    \
  __builtin_amdgcn_s_setprio(0);                                                         \
} while (0)

// One K-tile = 4 phases; ds-reads 12/4/8/0.
// ph0 has NO explicit lgkm drain: its reads are compiler-visible, so hipcc emits
// counted lgkmcnt(N) per MFMA (starts compute after first frags land). All ph0 reads
// retire (in-order DS FIFO) by end of ph0's MFMA cluster; ph1's LGKM0+barrier then
// globally post-dates every B-buf-c read before ph2/ph3 restage it. ph2's LGKM0
// covers A-half1 reads vs t+1-ph0's STAGE_A(...,1,c).
// vmcnt ledger: tile tau's 8 loads issue at (tau-2):ph2 [B0], (tau-2):ph3 [B1,A0],
// (tau-1):ph0 [A1]; at tile t ph3 drain, outstanding = t+2's 6 loads -> VMC6.
#define TILE(t_, c_, doS4, doS123, VMCODE) do {                                          \
  /* ph0 */                                                                              \
  LOAD_A(0, c_); LOAD_B01(c_);                                                           \
  if (doS4) STAGE_A((t_) + 1, 1, (c_) ^ 1);                                              \
  BARR(); MFMA_PH(0, 0); BARR();                                                         \
  /* ph1 */                                                                              \
  LOAD_B23(c_);                                                                          \
  BARR(); LGKM0(); MFMA_PH(0, 1); BARR();                                                \
  /* ph2 */                                                                              \
  LOAD_A(1, c_);                                                                         \
  if (doS123) STAGE_B((t_) + 2, 0, c_);                                                  \
  BARR(); LGKM0(); MFMA_PH(1, 1); BARR();                                                \
  /* ph3 */                                                                              \
  if (doS123) { STAGE_B((t_) + 2, 1, c_); STAGE_A((t_) + 2, 0, c_); }                    \
  BARR(); MFMA_PH(1, 0); VMCODE; BARR();                                                 \
} while (0)

__global__ __launch_bounds__(512, 2) void k_gemm(const unsigned short* __restrict__ A,
                                                 const unsigned short* __restrict__ B,
                                                 const float* __restrict__ bias,
                                                 float* __restrict__ C) {
  __shared__ char smem[131072];   // static 128 KiB (gfx950: 160 KiB/WG max)
  const int tid  = threadIdx.x;
  const int lane = tid & 63;
  const int wv   = tid >> 6;     // 0..7
  const int wm   = wv >> 2;      // 0..1
  const int wn   = wv & 3;       // 0..3
  const int r    = lane & 15;
  const int q    = lane >> 4;
  const int xr   = r & 7;
  const int coff0 = (q ^ xr) << 4;          // byte col for kk=0 (swizzled)
  const int coff1 = ((q + 4) ^ xr) << 4;    // byte col for kk=1
  const int rowA = (wm * 128 + r) * 128;    // byte row base in A tile
  const int rowB = (wn * 64 + r) * 128;     // byte row base in B tile
  const int srow = tid >> 3;                // 0..63 staging row
  const int scol = ((tid & 7) ^ ((tid >> 3) & 7)) * 8;  // pre-swizzled global elem col
  const int ldsw = wv * 1024;               // wave's byte slot in a staging round
  const int bm = blockIdx.x;                // 0..31
  const int bn = blockIdx.y;                // 0..15

  const unsigned short* Ag = A + (size_t)(bm * 256 + srow) * KDIM + scol;
  const unsigned short* Bg = B + (size_t)(bn * 256 + srow) * KDIM + scol;

  bf16x8 af[4][2], bfr[4][2];
  f32x4 acc[8][4];
  #pragma unroll
  for (int m = 0; m < 8; ++m)
    #pragma unroll
    for (int n = 0; n < 4; ++n)
      acc[m][n] = (f32x4){0.f, 0.f, 0.f, 0.f};

  // prologue: tile0 complete + 3 halves of tile1 (7 half-tiles, 14 loads/thread)
  STAGE_B(0, 0, 0); STAGE_B(0, 1, 0); STAGE_A(0, 0, 0); STAGE_A(0, 1, 0);
  STAGE_B(1, 0, 1); STAGE_B(1, 1, 1); STAGE_A(1, 0, 1);
  VMC6();   // tile0's 8 loads done; 6 in flight
  BARR();

  #pragma unroll 1
  for (int t = 0; t < 62; t += 2) {
    TILE(t,     0, 1, 1, VMC6());
    TILE(t + 1, 1, 1, 1, VMC6());
  }
  TILE(62, 0, 1, 0, VMC0());
  TILE(63, 1, 0, 0, VMC0());

  // epilogue: C = acc + bias  (C/D layout: col = r, row = q*4 + j)
  const int row0 = bm * 256 + wm * 128;
  const int col0 = bn * 256 + wn * 64;
  float bv[4];
  #pragma unroll
  for (int ni = 0; ni < 4; ++ni) bv[ni] = bias[col0 + ni * 16 + r];
  #pragma unroll
  for (int mi = 0; mi < 8; ++mi) {
    #pragma unroll
    for (int j = 0; j < 4; ++j) {
      const int row = row0 + mi * 16 + q * 4 + j;
      float* Cp = C + (size_t)row * OUT_F + col0 + r;
      #pragma unroll
      for (int ni = 0; ni < 4; ++ni)
        Cp[ni * 16] = acc[mi][ni][j] + bv[ni];
    }
  }
}

extern "C" void kernel_launch(void* const* d_in, const int* in_sizes, int n_in,
                              void* d_out, int out_size, void* d_ws, size_t ws_size,
                              hipStream_t stream) {
  const float* x    = (const float*)d_in[0];
  const int*   idx  = (const int*)d_in[1];
  const float* cb   = (const float*)d_in[2];
  const float* scl  = (const float*)d_in[3];
  const float* lA   = (const float*)d_in[4];
  const float* lB   = (const float*)d_in[5];
  const float* bias = (const float*)d_in[6];
  float* out = (float*)d_out;

  unsigned short* xb = (unsigned short*)d_ws;
  unsigned short* Wc = (unsigned short*)((char*)d_ws + (size_t)M_TOT * KDIM * 2);
  unsigned short* Lbuf = (unsigned short*)d_out;  // bf16 LoRA scratch; overwritten by k_gemm

  k_xcast<<<16384, 256, 0, stream>>>((const f32x4*)x, (u16x8*)xb);
  k_lora<<<dim3(16, 64), 256, 0, stream>>>(lA, lB, Lbuf);
  k_dequant<<<8192, 256, 0, stream>>>(idx, cb, scl, Lbuf, Wc);
  k_gemm<<<dim3(32, 16), 512, 0, stream>>>(xb, Wc, bias, out);
}

// Round 8
// 282.558 us; speedup vs baseline: 1.0607x; 1.0215x over previous
//
#include <hip/hip_runtime.h>
#include <stdint.h>

#define IN_F   4096
#define OUT_F  4096
#define M_TOT  8192
#define KDIM   4096

typedef float          f32x4  __attribute__((ext_vector_type(4)));
typedef int            i32x4  __attribute__((ext_vector_type(4)));
typedef unsigned short u16x8  __attribute__((ext_vector_type(8)));
typedef __bf16         bf16x8 __attribute__((ext_vector_type(8)));

// round-to-nearest-even f32 -> bf16
__device__ __forceinline__ unsigned short f2bf(float f) {
  uint32_t u = __builtin_bit_cast(uint32_t, f);
  u = (u + 0x7FFFu + ((u >> 16) & 1u)) >> 16;
  return (unsigned short)u;
}
__device__ __forceinline__ float bf2f(unsigned short s) {
  return __builtin_bit_cast(float, (uint32_t)s << 16);
}

// async global->LDS, 16B/lane; LDS dest = wave-uniform base + lane*16 (linear)
__device__ __forceinline__ void gld_lds16(const void* g, void* l) {
  __builtin_amdgcn_global_load_lds((const __attribute__((address_space(1))) void*)g,
                                   (__attribute__((address_space(3))) void*)l,
                                   16, 0, 0);
}

// ---------- kernel 1: x (fp32) -> bf16, 8 elems/thread ----------
__global__ __launch_bounds__(256) void k_xcast(const f32x4* __restrict__ x,
                                               u16x8* __restrict__ xb) {
  int t = blockIdx.x * 256 + threadIdx.x;
  f32x4 a = x[2 * t];
  f32x4 b = x[2 * t + 1];
  u16x8 o;
  o[0] = f2bf(a[0]); o[1] = f2bf(a[1]); o[2] = f2bf(a[2]); o[3] = f2bf(a[3]);
  o[4] = f2bf(b[0]); o[5] = f2bf(b[1]); o[6] = f2bf(b[2]); o[7] = f2bf(b[3]);
  xb[t] = o;
}

// ---------- kernel 2: L[o][i] = bf16( 2.0 * sum_r A[i][r]*B[r][o] )  (into d_out scratch) ----------
__global__ __launch_bounds__(256) void k_lora(const float* __restrict__ A,   // [IN_F][16]
                                              const float* __restrict__ Bm,  // [16][OUT_F]
                                              unsigned short* __restrict__ L) { // [OUT_F][IN_F] bf16
  __shared__ float sB[16][64];
  const int ib = blockIdx.x * 256;
  const int ob = blockIdx.y * 64;
  const int t  = threadIdx.x;
  for (int j = 0; j < 4; ++j) {
    int idx = t + j * 256;
    int r = idx >> 6, oc = idx & 63;
    sB[r][oc] = Bm[r * OUT_F + ob + oc];
  }
  float a[16];
  const f32x4* Ap = (const f32x4*)(A + (size_t)(ib + t) * 16);
  #pragma unroll
  for (int j = 0; j < 4; ++j) {
    f32x4 v = Ap[j];
    a[4*j+0] = v[0]; a[4*j+1] = v[1]; a[4*j+2] = v[2]; a[4*j+3] = v[3];
  }
  __syncthreads();
  unsigned short* Lp = L + (size_t)ob * IN_F + ib + t;
  #pragma unroll 4
  for (int oc = 0; oc < 64; ++oc) {
    float acc = 0.f;
    #pragma unroll
    for (int r = 0; r < 16; ++r) acc += a[r] * sB[r][oc];
    Lp[(size_t)oc * IN_F] = f2bf(acc * 2.0f);   // LORA_SCALE = 32/16
  }
}

// ---------- kernel 3: dequant INT4 + merge L -> Wc bf16 [OUT_F][IN_F] ----------
__global__ __launch_bounds__(256) void k_dequant(const int* __restrict__ idx,
                                                 const float* __restrict__ cb,
                                                 const float* __restrict__ scales,
                                                 const unsigned short* __restrict__ L,
                                                 unsigned short* __restrict__ Wc) {
  __shared__ float scb[16];
  const int t = blockIdx.x * 256 + threadIdx.x;
  if (threadIdx.x < 16) scb[threadIdx.x] = cb[threadIdx.x];
  __syncthreads();
  i32x4 w = ((const i32x4*)idx)[t];
  float sc = scales[t >> 4];
  u16x8 lw = ((const u16x8*)L)[t];
  u16x8 o;
  #pragma unroll
  for (int j = 0; j < 4; ++j) {
    int word = w[j];
    float v0 = scb[word & 15] * sc + bf2f(lw[2 * j]);
    float v1 = scb[(word >> 4) & 15] * sc + bf2f(lw[2 * j + 1]);
    o[2 * j]     = f2bf(v0);
    o[2 * j + 1] = f2bf(v1);
  }
  ((u16x8*)Wc)[t] = o;
}

// ---------- kernel 4: 256x256 8-phase bf16 GEMM (m201-style template) ----------
// C[m][n] = sum_k A[m][k]*B[n][k] + bias[n];  A:[8192][4096] bf16, B:[4096][4096] bf16.
// 512 threads = 8 waves (2M x 4N); per-wave output 128x64; BK=64; 128 KiB static LDS dbuf.
// LDS layout (bytes): A buf c at c*32768 (256 rows x 128B); B buf c at 65536+c*32768.
// Swizzle: logical 16B-slot s of row is stored at physical slot s^(row&7);
// applied via pre-swizzled global source (linear gld_lds dest) + XOR on ds_read.
// Grid: natural dim3(32,16) — resident set per XCD = 4bm x 8bn (~384KB/K-step in L2).
// K-loop = round-4 best-measured form (reads 16/0/8/0, LGKM0 at ph0/ph2, stages 2/2/2/2).

#define BARR()  __builtin_amdgcn_s_barrier()
#define LGKM0() asm volatile("s_waitcnt lgkmcnt(0)" ::: "memory")
#define VMC6()  asm volatile("s_waitcnt vmcnt(6)" ::: "memory")
#define VMC0()  asm volatile("s_waitcnt vmcnt(0)" ::: "memory")

#define STAGE_A(kt, ha, c) do {                                                          \
  gld_lds16(Ag + (size_t)((ha) * 128) * KDIM + (kt) * 64,                                \
            smem + (c) * 32768 + (ha) * 16384 + ldsw);                                   \
  gld_lds16(Ag + (size_t)((ha) * 128 + 64) * KDIM + (kt) * 64,                           \
            smem + (c) * 32768 + (ha) * 16384 + 8192 + ldsw);                            \
} while (0)

#define STAGE_B(kt, hb, c) do {                                                          \
  gld_lds16(Bg + (size_t)((hb) * 128) * KDIM + (kt) * 64,                                \
            smem + 65536 + (c) * 32768 + (hb) * 16384 + ldsw);                           \
  gld_lds16(Bg + (size_t)((hb) * 128 + 64) * KDIM + (kt) * 64,                           \
            smem + 65536 + (c) * 32768 + (hb) * 16384 + 8192 + ldsw);                    \
} while (0)

#define LOAD_A(qm, c) do {                                                               \
  const char* _p = smem + (c) * 32768 + rowA + (qm) * 8192;                              \
  _Pragma("unroll")                                                                      \
  for (int mi = 0; mi < 4; ++mi) {                                                       \
    af[mi][0] = *(const bf16x8*)(_p + mi * 2048 + coff0);                                \
    af[mi][1] = *(const bf16x8*)(_p + mi * 2048 + coff1);                                \
  }                                                                                      \
} while (0)

#define LOAD_B(c) do {                                                                   \
  const char* _p = smem + 65536 + (c) * 32768 + rowB;                                    \
  _Pragma("unroll")                                                                      \
  for (int ni = 0; ni < 4; ++ni) {                                                       \
    bfr[ni][0] = *(const bf16x8*)(_p + ni * 2048 + coff0);                               \
    bfr[ni][1] = *(const bf16x8*)(_p + ni * 2048 + coff1);                               \
  }                                                                                      \
} while (0)

#define MFMA_PH(qm, nb) do {                                                             \
  __builtin_amdgcn_s_setprio(1);                                                         \
  _Pragma("unroll")                                                                      \
  for (int mi = 0; mi < 4; ++mi)                                                         \
    _Pragma("unroll")                                                                    \
    for (int nj = 0; nj < 2; ++nj)                                                       \
      _Pragma("unroll")                                                                  \
      for (int kk = 0; kk < 2; ++kk)                                                     \
        acc[(qm) * 4 + mi][(nb) * 2 + nj] = __builtin_amdgcn_mfma_f32_16x16x32_bf16(     \
            af[mi][kk], bfr[(nb) * 2 + nj][kk], acc[(qm) * 4 + mi][(nb) * 2 + nj],       \
            0, 0, 0);                                                                    \
  __builtin_amdgcn_s_setprio(0);                                                         \
} while (0)

// One K-tile = 4 phases (round-4 form). Stage order: S4(t+1) ph0, S1(t+2) ph1,
// S2(t+2) ph2, S3(t+2) ph3. All B reads in ph0 (retired by ph0's LGKM0+barrier);
// A-half1 reads retire at ph2's LGKM0+barrier. vmcnt ledger: at tile t ph3 drain,
// outstanding = t+2's 6 loads -> VMC6; tile t+1's buffers all complete.
#define TILE(t_, c_, doS4, doS123, VMCODE) do {                                          \
  /* ph0 */                                                                              \
  LOAD_A(0, c_); LOAD_B(c_);                                                             \
  if (doS4) STAGE_A((t_) + 1, 1, (c_) ^ 1);                                              \
  BARR(); LGKM0(); MFMA_PH(0, 0); BARR();                                                \
  /* ph1 */                                                                              \
  if (doS123) STAGE_B((t_) + 2, 0, c_);                                                  \
  BARR(); MFMA_PH(0, 1); BARR();                                                         \
  /* ph2 */                                                                              \
  LOAD_A(1, c_);                                                                         \
  if (doS123) STAGE_B((t_) + 2, 1, c_);                                                  \
  BARR(); LGKM0(); MFMA_PH(1, 1); BARR();                                                \
  /* ph3 */                                                                              \
  if (doS123) STAGE_A((t_) + 2, 0, c_);                                                  \
  BARR(); MFMA_PH(1, 0); VMCODE; BARR();                                                 \
} while (0)

__global__ __launch_bounds__(512, 2) void k_gemm(const unsigned short* __restrict__ A,
                                                 const unsigned short* __restrict__ B,
                                                 const float* __restrict__ bias,
                                                 float* __restrict__ C) {
  __shared__ char smem[131072];   // static 128 KiB (gfx950: 160 KiB/WG max)
  const int tid  = threadIdx.x;
  const int lane = tid & 63;
  const int wv   = tid >> 6;     // 0..7
  const int wm   = wv >> 2;      // 0..1
  const int wn   = wv & 3;       // 0..3
  const int r    = lane & 15;
  const int q    = lane >> 4;
  const int xr   = r & 7;
  const int coff0 = (q ^ xr) << 4;          // byte col for kk=0 (swizzled)
  const int coff1 = ((q + 4) ^ xr) << 4;    // byte col for kk=1
  const int rowA = (wm * 128 + r) * 128;    // byte row base in A tile
  const int rowB = (wn * 64 + r) * 128;     // byte row base in B tile
  const int srow = tid >> 3;                // 0..63 staging row
  const int scol = ((tid & 7) ^ ((tid >> 3) & 7)) * 8;  // pre-swizzled global elem col
  const int ldsw = wv * 1024;               // wave's byte slot in a staging round
  const int bm = blockIdx.x;                // 0..31
  const int bn = blockIdx.y;                // 0..15

  const unsigned short* Ag = A + (size_t)(bm * 256 + srow) * KDIM + scol;
  const unsigned short* Bg = B + (size_t)(bn * 256 + srow) * KDIM + scol;

  bf16x8 af[4][2], bfr[4][2];
  f32x4 acc[8][4];
  #pragma unroll
  for (int m = 0; m < 8; ++m)
    #pragma unroll
    for (int n = 0; n < 4; ++n)
      acc[m][n] = (f32x4){0.f, 0.f, 0.f, 0.f};

  // prologue: tile0 complete + 3 halves of tile1 (7 half-tiles, 14 loads/thread)
  STAGE_B(0, 0, 0); STAGE_B(0, 1, 0); STAGE_A(0, 0, 0); STAGE_A(0, 1, 0);
  STAGE_B(1, 0, 1); STAGE_B(1, 1, 1); STAGE_A(1, 0, 1);
  VMC6();   // tile0's 8 loads done; 6 in flight
  BARR();

  #pragma unroll 1
  for (int t = 0; t < 62; t += 2) {
    TILE(t,     0, 1, 1, VMC6());
    TILE(t + 1, 1, 1, 1, VMC6());
  }
  TILE(62, 0, 1, 0, VMC0());
  TILE(63, 1, 0, 0, VMC0());

  // ---- epilogue: LDS-repack + coalesced dwordx4 stores ----
  // ROUND-7 BUG FIX: raw s_barrier is IntrNoMem (no compiler memory fence), so
  // epilogue ds_writes could hoist across it into tile-63's live A/B buffers.
  // Three safety layers here:
  //  (1) eps lives in A-buf0 [0,32KiB), provably dead through TILE(63) (last
  //      buf0 reads retire in TILE(62) ph2; last buf0 stages issued TILE(61));
  //      even a worst-case hoist to TILE(63)-ph0's LGKM0 cannot race.
  //  (2) __syncthreads() = waitcnt+barrier WITH fence semantics (motion stop).
  //  (3) in-wave scatter->gather ordered by lgkmcnt(0) asm ("memory") +
  //      sched_barrier(0); gather->next-scatter by a compiler memory fence.
  // acc C/D layout: col = r + ni*16, row-in-16 = q*4 + j.
  __syncthreads();
  {
    char* eps = smem + wv * 4096;             // [16 rows][64 f32], within A-buf0
    const int row0 = bm * 256 + wm * 128;
    const int col0 = bn * 256 + wn * 64;
    const f32x4 bias4 = *(const f32x4*)(bias + col0 + r * 4);
    #pragma unroll
    for (int mi = 0; mi < 8; ++mi) {
      // scatter: 16 scalar ds_writes
      #pragma unroll
      for (int j = 0; j < 4; ++j)
        #pragma unroll
        for (int ni = 0; ni < 4; ++ni)
          *(float*)(eps + (((q * 4 + j) * 64) + ni * 16 + r) * 4) = acc[mi][ni][j];
      LGKM0();
      __builtin_amdgcn_sched_barrier(0);
      // gather: 4 contiguous b128 reads + bias + coalesced dwordx4 stores
      #pragma unroll
      for (int p = 0; p < 4; ++p) {
        const int row = p * 4 + q;            // 0..15
        f32x4 v = *(const f32x4*)(eps + row * 256 + r * 16);
        v[0] += bias4[0]; v[1] += bias4[1]; v[2] += bias4[2]; v[3] += bias4[3];
        *(f32x4*)(C + (size_t)(row0 + mi * 16 + row) * OUT_F + col0 + r * 4) = v;
      }
      asm volatile("" ::: "memory");          // gather(mi) before scatter(mi+1)
    }
  }
}

extern "C" void kernel_launch(void* const* d_in, const int* in_sizes, int n_in,
                              void* d_out, int out_size, void* d_ws, size_t ws_size,
                              hipStream_t stream) {
  const float* x    = (const float*)d_in[0];
  const int*   idx  = (const int*)d_in[1];
  const float* cb   = (const float*)d_in[2];
  const float* scl  = (const float*)d_in[3];
  const float* lA   = (const float*)d_in[4];
  const float* lB   = (const float*)d_in[5];
  const float* bias = (const float*)d_in[6];
  float* out = (float*)d_out;

  unsigned short* xb = (unsigned short*)d_ws;
  unsigned short* Wc = (unsigned short*)((char*)d_ws + (size_t)M_TOT * KDIM * 2);
  unsigned short* Lbuf = (unsigned short*)d_out;  // bf16 LoRA scratch; overwritten by k_gemm

  k_xcast<<<16384, 256, 0, stream>>>((const f32x4*)x, (u16x8*)xb);
  k_lora<<<dim3(16, 64), 256, 0, stream>>>(lA, lB, Lbuf);
  k_dequant<<<8192, 256, 0, stream>>>(idx, cb, scl, Lbuf, Wc);
  k_gemm<<<dim3(32, 16), 512, 0, stream>>>(xb, Wc, bias, out);
}

// Round 9
// 280.482 us; speedup vs baseline: 1.0686x; 1.0074x over previous
//
#include <hip/hip_runtime.h>
#include <stdint.h>

#define IN_F   4096
#define OUT_F  4096
#define M_TOT  8192
#define KDIM   4096

typedef float          f32x4  __attribute__((ext_vector_type(4)));
typedef int            i32x4  __attribute__((ext_vector_type(4)));
typedef unsigned short u16x8  __attribute__((ext_vector_type(8)));
typedef __bf16         bf16x8 __attribute__((ext_vector_type(8)));

// round-to-nearest-even f32 -> bf16
__device__ __forceinline__ unsigned short f2bf(float f) {
  uint32_t u = __builtin_bit_cast(uint32_t, f);
  u = (u + 0x7FFFu + ((u >> 16) & 1u)) >> 16;
  return (unsigned short)u;
}
__device__ __forceinline__ float bf2f(unsigned short s) {
  return __builtin_bit_cast(float, (uint32_t)s << 16);
}

// async global->LDS, 16B/lane; LDS dest = wave-uniform base + lane*16 (linear)
__device__ __forceinline__ void gld_lds16(const void* g, void* l) {
  __builtin_amdgcn_global_load_lds((const __attribute__((address_space(1))) void*)g,
                                   (__attribute__((address_space(3))) void*)l,
                                   16, 0, 0);
}

// ---------- kernel 1: x (fp32) -> bf16, 8 elems/thread ----------
__global__ __launch_bounds__(256) void k_xcast(const f32x4* __restrict__ x,
                                               u16x8* __restrict__ xb) {
  int t = blockIdx.x * 256 + threadIdx.x;
  f32x4 a = x[2 * t];
  f32x4 b = x[2 * t + 1];
  u16x8 o;
  o[0] = f2bf(a[0]); o[1] = f2bf(a[1]); o[2] = f2bf(a[2]); o[3] = f2bf(a[3]);
  o[4] = f2bf(b[0]); o[5] = f2bf(b[1]); o[6] = f2bf(b[2]); o[7] = f2bf(b[3]);
  xb[t] = o;
}

// ---------- kernel 2: L[o][i] = bf16( 2.0 * sum_r A[i][r]*B[r][o] )  (into d_out scratch) ----------
__global__ __launch_bounds__(256) void k_lora(const float* __restrict__ A,   // [IN_F][16]
                                              const float* __restrict__ Bm,  // [16][OUT_F]
                                              unsigned short* __restrict__ L) { // [OUT_F][IN_F] bf16
  __shared__ float sB[16][64];
  const int ib = blockIdx.x * 256;
  const int ob = blockIdx.y * 64;
  const int t  = threadIdx.x;
  for (int j = 0; j < 4; ++j) {
    int idx = t + j * 256;
    int r = idx >> 6, oc = idx & 63;
    sB[r][oc] = Bm[r * OUT_F + ob + oc];
  }
  float a[16];
  const f32x4* Ap = (const f32x4*)(A + (size_t)(ib + t) * 16);
  #pragma unroll
  for (int j = 0; j < 4; ++j) {
    f32x4 v = Ap[j];
    a[4*j+0] = v[0]; a[4*j+1] = v[1]; a[4*j+2] = v[2]; a[4*j+3] = v[3];
  }
  __syncthreads();
  unsigned short* Lp = L + (size_t)ob * IN_F + ib + t;
  #pragma unroll 4
  for (int oc = 0; oc < 64; ++oc) {
    float acc = 0.f;
    #pragma unroll
    for (int r = 0; r < 16; ++r) acc += a[r] * sB[r][oc];
    Lp[(size_t)oc * IN_F] = f2bf(acc * 2.0f);   // LORA_SCALE = 32/16
  }
}

// ---------- kernel 3: dequant INT4 + merge L -> Wc bf16 [OUT_F][IN_F] ----------
__global__ __launch_bounds__(256) void k_dequant(const int* __restrict__ idx,
                                                 const float* __restrict__ cb,
                                                 const float* __restrict__ scales,
                                                 const unsigned short* __restrict__ L,
                                                 unsigned short* __restrict__ Wc) {
  __shared__ float scb[16];
  const int t = blockIdx.x * 256 + threadIdx.x;
  if (threadIdx.x < 16) scb[threadIdx.x] = cb[threadIdx.x];
  __syncthreads();
  i32x4 w = ((const i32x4*)idx)[t];
  float sc = scales[t >> 4];
  u16x8 lw = ((const u16x8*)L)[t];
  u16x8 o;
  #pragma unroll
  for (int j = 0; j < 4; ++j) {
    int word = w[j];
    float v0 = scb[word & 15] * sc + bf2f(lw[2 * j]);
    float v1 = scb[(word >> 4) & 15] * sc + bf2f(lw[2 * j + 1]);
    o[2 * j]     = f2bf(v0);
    o[2 * j + 1] = f2bf(v1);
  }
  ((u16x8*)Wc)[t] = o;
}

// ---------- kernel 4: 256x256 bf16 GEMM, 2-deep single-barrier pipeline ----------
// C[m][n] = sum_k A[m][k]*B[n][k] + bias[n];  A:[8192][4096] bf16, B:[4096][4096] bf16.
// 512 threads = 8 waves (2M x 4N); per-wave output 128x64; BK=64; 128 KiB static LDS dbuf.
// LDS layout (bytes): A buf c at c*32768 (256 rows x 128B); B buf c at 65536+c*32768.
// Swizzle: logical 16B-slot s of row is stored at physical slot s^(row&7);
// applied via pre-swizzled global source (linear gld_lds dest) + XOR on ds_read.
// Grid: natural dim3(32,16) — resident set per XCD = 4bm x 8bn (~L2-friendly).
//
// ROUND-9 RESTRUCTURE (from round-8 counter model): the 8-barrier/tile lockstep
// time-sliced LDS (~50%) against MFMA (~52%) -> 4490 cyc/tile. Going 2-deep
// (tile t stages ALL of t+1 into buf c^1, whose readers retired last tile)
// removes every intra-tile WAR fence: body = [stage 8] [24 ds_reads buf c]
// [64 MFMA] LGKM0 VMC0 BARR — ONE barrier + ONE vmcnt per tile. Waves de-sync
// within a tile (LDS bursts overlap other waves' MFMA); compiler emits
// fine-grained lgkmcnt for read->MFMA (m97-verified). VMC0 waits on loads
// issued a full tile (~2700+ cyc) earlier >> HBM latency.

#define BARR()  __builtin_amdgcn_s_barrier()
#define LGKM0() asm volatile("s_waitcnt lgkmcnt(0)" ::: "memory")
#define VMC0()  asm volatile("s_waitcnt vmcnt(0)" ::: "memory")

#define STAGE_A(kt, ha, c) do {                                                          \
  gld_lds16(Ag + (size_t)((ha) * 128) * KDIM + (kt) * 64,                                \
            smem + (c) * 32768 + (ha) * 16384 + ldsw);                                   \
  gld_lds16(Ag + (size_t)((ha) * 128 + 64) * KDIM + (kt) * 64,                           \
            smem + (c) * 32768 + (ha) * 16384 + 8192 + ldsw);                            \
} while (0)

#define STAGE_B(kt, hb, c) do {                                                          \
  gld_lds16(Bg + (size_t)((hb) * 128) * KDIM + (kt) * 64,                                \
            smem + 65536 + (c) * 32768 + (hb) * 16384 + ldsw);                           \
  gld_lds16(Bg + (size_t)((hb) * 128 + 64) * KDIM + (kt) * 64,                           \
            smem + 65536 + (c) * 32768 + (hb) * 16384 + 8192 + ldsw);                    \
} while (0)

#define LOAD_AH(DST, qm, c) do {                                                         \
  const char* _p = smem + (c) * 32768 + rowA + (qm) * 8192;                              \
  _Pragma("unroll")                                                                      \
  for (int mi = 0; mi < 4; ++mi) {                                                       \
    DST[mi][0] = *(const bf16x8*)(_p + mi * 2048 + coff0);                               \
    DST[mi][1] = *(const bf16x8*)(_p + mi * 2048 + coff1);                               \
  }                                                                                      \
} while (0)

#define LOAD_B(c) do {                                                                   \
  const char* _p = smem + 65536 + (c) * 32768 + rowB;                                    \
  _Pragma("unroll")                                                                      \
  for (int ni = 0; ni < 4; ++ni) {                                                       \
    bfr[ni][0] = *(const bf16x8*)(_p + ni * 2048 + coff0);                               \
    bfr[ni][1] = *(const bf16x8*)(_p + ni * 2048 + coff1);                               \
  }                                                                                      \
} while (0)

#define MFMA_PH(qm, nb, AF) do {                                                         \
  __builtin_amdgcn_s_setprio(1);                                                         \
  _Pragma("unroll")                                                                      \
  for (int mi = 0; mi < 4; ++mi)                                                         \
    _Pragma("unroll")                                                                    \
    for (int nj = 0; nj < 2; ++nj)                                                       \
      _Pragma("unroll")                                                                  \
      for (int kk = 0; kk < 2; ++kk)                                                     \
        acc[(qm) * 4 + mi][(nb) * 2 + nj] = __builtin_amdgcn_mfma_f32_16x16x32_bf16(     \
            AF[mi][kk], bfr[(nb) * 2 + nj][kk], acc[(qm) * 4 + mi][(nb) * 2 + nj],       \
            0, 0, 0);                                                                    \
  __builtin_amdgcn_s_setprio(0);                                                         \
} while (0)

// Tile t, buffer c = t&1. doStage => stage tile t+1 into buf c^1 (dead region:
// its readers drained at tile t-1's LGKM0+BARR). End-of-tile LGKM0 guarantees
// this tile's buf-c reads are globally retired before tile t+1's stage issue;
// VMC0 guarantees buf c^1 fully written before tile t+1 reads it; BARR makes
// both cross-wave. No other fences needed: stage targets never alias in-flight
// reads within a tile.
#define TILE2(t_, c_, doStage) do {                                                      \
  if (doStage) {                                                                         \
    STAGE_B((t_) + 1, 0, (c_) ^ 1); STAGE_B((t_) + 1, 1, (c_) ^ 1);                      \
    STAGE_A((t_) + 1, 0, (c_) ^ 1); STAGE_A((t_) + 1, 1, (c_) ^ 1);                      \
  }                                                                                      \
  LOAD_AH(afA, 0, c_); LOAD_B(c_); LOAD_AH(afB, 1, c_);                                  \
  MFMA_PH(0, 0, afA); MFMA_PH(0, 1, afA);                                                \
  MFMA_PH(1, 1, afB); MFMA_PH(1, 0, afB);                                                \
  LGKM0(); VMC0(); BARR();                                                               \
} while (0)

__global__ __launch_bounds__(512, 2) void k_gemm(const unsigned short* __restrict__ A,
                                                 const unsigned short* __restrict__ B,
                                                 const float* __restrict__ bias,
                                                 float* __restrict__ C) {
  __shared__ char smem[131072];   // static 128 KiB (gfx950: 160 KiB/WG max)
  const int tid  = threadIdx.x;
  const int lane = tid & 63;
  const int wv   = tid >> 6;     // 0..7
  const int wm   = wv >> 2;      // 0..1
  const int wn   = wv & 3;       // 0..3
  const int r    = lane & 15;
  const int q    = lane >> 4;
  const int xr   = r & 7;
  const int coff0 = (q ^ xr) << 4;          // byte col for kk=0 (swizzled)
  const int coff1 = ((q + 4) ^ xr) << 4;    // byte col for kk=1
  const int rowA = (wm * 128 + r) * 128;    // byte row base in A tile
  const int rowB = (wn * 64 + r) * 128;     // byte row base in B tile
  const int srow = tid >> 3;                // 0..63 staging row
  const int scol = ((tid & 7) ^ ((tid >> 3) & 7)) * 8;  // pre-swizzled global elem col
  const int ldsw = wv * 1024;               // wave's byte slot in a staging round
  const int bm = blockIdx.x;                // 0..31
  const int bn = blockIdx.y;                // 0..15

  const unsigned short* Ag = A + (size_t)(bm * 256 + srow) * KDIM + scol;
  const unsigned short* Bg = B + (size_t)(bn * 256 + srow) * KDIM + scol;

  bf16x8 afA[4][2], afB[4][2], bfr[4][2];
  f32x4 acc[8][4];
  #pragma unroll
  for (int m = 0; m < 8; ++m)
    #pragma unroll
    for (int n = 0; n < 4; ++n)
      acc[m][n] = (f32x4){0.f, 0.f, 0.f, 0.f};

  // prologue: stage tile 0 into buf0, wait, one barrier
  STAGE_B(0, 0, 0); STAGE_B(0, 1, 0); STAGE_A(0, 0, 0); STAGE_A(0, 1, 0);
  VMC0();
  BARR();

  #pragma unroll 1
  for (int t = 0; t < 62; t += 2) {
    TILE2(t,     0, 1);
    TILE2(t + 1, 1, 1);
  }
  TILE2(62, 0, 1);
  TILE2(63, 1, 0);

  // ---- epilogue: LDS-repack + coalesced dwordx4 stores (round-8 verified) ----
  // eps lives in A-buf0 [0,32KiB): last buf0 writes = stage at t61; last buf0
  // reads = t62's ds_reads (drained at t62's LGKM0+BARR). __syncthreads() gives
  // the compiler-level fence the raw s_barrier lacks.
  __syncthreads();
  {
    char* eps = smem + wv * 4096;             // [16 rows][64 f32], within A-buf0
    const int row0 = bm * 256 + wm * 128;
    const int col0 = bn * 256 + wn * 64;
    const f32x4 bias4 = *(const f32x4*)(bias + col0 + r * 4);
    #pragma unroll
    for (int mi = 0; mi < 8; ++mi) {
      #pragma unroll
      for (int j = 0; j < 4; ++j)
        #pragma unroll
        for (int ni = 0; ni < 4; ++ni)
          *(float*)(eps + (((q * 4 + j) * 64) + ni * 16 + r) * 4) = acc[mi][ni][j];
      LGKM0();
      __builtin_amdgcn_sched_barrier(0);
      #pragma unroll
      for (int p = 0; p < 4; ++p) {
        const int row = p * 4 + q;            // 0..15
        f32x4 v = *(const f32x4*)(eps + row * 256 + r * 16);
        v[0] += bias4[0]; v[1] += bias4[1]; v[2] += bias4[2]; v[3] += bias4[3];
        *(f32x4*)(C + (size_t)(row0 + mi * 16 + row) * OUT_F + col0 + r * 4) = v;
      }
      asm volatile("" ::: "memory");          // gather(mi) before scatter(mi+1)
    }
  }
}

extern "C" void kernel_launch(void* const* d_in, const int* in_sizes, int n_in,
                              void* d_out, int out_size, void* d_ws, size_t ws_size,
                              hipStream_t stream) {
  const float* x    = (const float*)d_in[0];
  const int*   idx  = (const int*)d_in[1];
  const float* cb   = (const float*)d_in[2];
  const float* scl  = (const float*)d_in[3];
  const float* lA   = (const float*)d_in[4];
  const float* lB   = (const float*)d_in[5];
  const float* bias = (const float*)d_in[6];
  float* out = (float*)d_out;

  unsigned short* xb = (unsigned short*)d_ws;
  unsigned short* Wc = (unsigned short*)((char*)d_ws + (size_t)M_TOT * KDIM * 2);
  unsigned short* Lbuf = (unsigned short*)d_out;  // bf16 LoRA scratch; overwritten by k_gemm

  k_xcast<<<16384, 256, 0, stream>>>((const f32x4*)x, (u16x8*)xb);
  k_lora<<<dim3(16, 64), 256, 0, stream>>>(lA, lB, Lbuf);
  k_dequant<<<8192, 256, 0, stream>>>(idx, cb, scl, Lbuf, Wc);
  k_gemm<<<dim3(32, 16), 512, 0, stream>>>(xb, Wc, bias, out);
}